// Round 3
// baseline (319.080 us; speedup 1.0000x reference)
//
#include <hip/hip_runtime.h>

#define BATCH 256
#define IMH 320
#define IMW 320
#define OUTD 314            // 320 - 7 + 1
#define WIN7 7
#define TOX 122             // output cols per tile (+6 halo = 128 threads)
#define RCH 80              // output rows per chunk

// ---------------- kernel 1: per-sample max(Y) ----------------
__global__ __launch_bounds__(256) void k_max(const float* __restrict__ Y,
                                             unsigned* __restrict__ dr) {
    int bid = blockIdx.x;
    int b = bid >> 2, part = bid & 3;           // 4 blocks per sample
    const float4* p = (const float4*)(Y + (size_t)b * (IMH * IMW) + part * (IMH * IMW / 4));
    float m = 0.f;
    for (int i = threadIdx.x; i < (IMH * IMW / 16); i += 256) {
        float4 v = p[i];
        m = fmaxf(m, fmaxf(fmaxf(v.x, v.y), fmaxf(v.z, v.w)));
    }
    for (int off = 32; off; off >>= 1) m = fmaxf(m, __shfl_down(m, off, 64));
    __shared__ float sm[4];
    int lane = threadIdx.x & 63, wv = threadIdx.x >> 6;
    if (lane == 0) sm[wv] = m;
    __syncthreads();
    if (threadIdx.x == 0) {
        m = fmaxf(fmaxf(sm[0], sm[1]), fmaxf(sm[2], sm[3]));
        atomicMax(dr + b, __float_as_uint(m));   // Y in (0,1): uint order == float order
    }
}

// ---------------- kernel 2: fused box filters + SSIM + partial sum ----------------
__global__ __launch_bounds__(128) void k_ssim(const float* __restrict__ X,
                                              const float* __restrict__ Y,
                                              const unsigned* __restrict__ dr,
                                              double* __restrict__ acc) {
    int idx = blockIdx.x;
    int b = idx / 12;
    int rem = idx - b * 12;
    int ct = rem % 3;          // column tile 0..2
    int rc = rem / 3;          // row chunk 0..3
    int t  = threadIdx.x;
    int c  = ct * TOX + t;     // input column this thread owns
    int r0 = rc * RCH;
    int nout = min(RCH, OUTD - r0);
    bool colload = (c < IMW);

    const size_t base = (size_t)b * (IMH * IMW);
    const float* Xp = X + base;
    const float* Yp = Y + base;

    float drv = __uint_as_float(dr[b]);
    float c1r = 0.01f * drv, c2r = 0.03f * drv;
    float C1 = c1r * c1r;
    float C2 = c2r * c2r;

    __shared__ float vs[5][132];   // 5 column-sum quantities, 128 cols (+pad)

    // 7-row history, statically rotated (no runtime indexing -> stays in VGPRs)
    float x0=0,x1=0,x2=0,x3=0,x4=0,x5=0,x6=0;
    float y0=0,y1=0,y2=0,y3=0,y4=0,y5=0,y6=0;
    float sx=0, sy=0, sxx=0, syy=0, sxy=0;
    float part = 0.f;

    int rend = r0 + nout + (WIN7 - 2);   // inclusive last input row
    for (int r = r0; r <= rend; ++r) {
        float xn = 0.f, yn = 0.f;
        if (colload) {
            xn = Xp[(size_t)r * IMW + c];
            yn = Yp[(size_t)r * IMW + c];
        }
        // sliding vertical sums over 7 rows
        sx  += xn - x0;
        sy  += yn - y0;
        sxx += xn * xn - x0 * x0;
        syy += yn * yn - y0 * y0;
        sxy += xn * yn - x0 * y0;
        x0=x1; x1=x2; x2=x3; x3=x4; x4=x5; x5=x6; x6=xn;
        y0=y1; y1=y2; y2=y3; y3=y4; y4=y5; y5=y6; y6=yn;

        if (r - r0 >= WIN7 - 1) {      // uniform across block
            vs[0][t]=sx; vs[1][t]=sy; vs[2][t]=sxx; vs[3][t]=syy; vs[4][t]=sxy;
            __syncthreads();
            int co = ct * TOX + t;     // output column
            if (t < TOX && co < OUTD) {
                float hsx=0, hsy=0, hsxx=0, hsyy=0, hsxy=0;
                #pragma unroll
                for (int d = 0; d < WIN7; ++d) {
                    hsx  += vs[0][t + d];
                    hsy  += vs[1][t + d];
                    hsxx += vs[2][t + d];
                    hsyy += vs[3][t + d];
                    hsxy += vs[4][t + d];
                }
                const float inv = 1.f / 49.f;
                const float cn  = 49.f / 48.f;
                float ux  = hsx  * inv, uy  = hsy  * inv;
                float uxx = hsxx * inv, uyy = hsyy * inv, uxy = hsxy * inv;
                float vx  = cn * (uxx - ux * ux);
                float vy  = cn * (uyy - uy * uy);
                float vxy = cn * (uxy - ux * uy);
                float A1 = 2.f * ux * uy + C1;
                float A2 = 2.f * vxy + C2;
                float B1 = ux * ux + uy * uy + C1;
                float B2 = vx + vy + C2;
                part += (A1 * A2) / (B1 * B2);
            }
            __syncthreads();
        }
    }

    // block reduction of partial SSIM sum
    for (int off = 32; off; off >>= 1) part += __shfl_down(part, off, 64);
    __shared__ float ps[2];
    if ((threadIdx.x & 63) == 0) ps[threadIdx.x >> 6] = part;
    __syncthreads();
    if (threadIdx.x == 0) atomicAdd(acc, (double)(ps[0] + ps[1]));
}

// ---------------- kernel 3: finalize ----------------
__global__ void k_final(const double* __restrict__ acc, float* __restrict__ out) {
    const double cnt = (double)BATCH * (double)OUTD * (double)OUTD;
    out[0] = (float)(1.0 - acc[0] / cnt);
}

extern "C" void kernel_launch(void* const* d_in, const int* in_sizes, int n_in,
                              void* d_out, int out_size, void* d_ws, size_t ws_size,
                              hipStream_t stream) {
    const float* X = (const float*)d_in[0];
    const float* Y = (const float*)d_in[1];
    float* out = (float*)d_out;

    unsigned* dr = (unsigned*)d_ws;                      // 256 * 4 B
    double* acc  = (double*)((char*)d_ws + 1024);        // 8 B, aligned

    hipMemsetAsync(d_ws, 0, 2048, stream);               // zero dr + acc
    k_max <<<BATCH * 4, 256, 0, stream>>>(Y, dr);
    k_ssim<<<BATCH * 12, 128, 0, stream>>>(X, Y, dr, acc);
    k_final<<<1, 1, 0, stream>>>(acc, out);
}

// Round 6
// 281.254 us; speedup vs baseline: 1.1345x; 1.1345x over previous
//
#include <hip/hip_runtime.h>

#define BATCH 256
#define IMH 320
#define IMW 320
#define OUTD 314            // 320 - 7 + 1
#define NCH 9               // row chunks per sample
#define RCH 36              // output rows per chunk (last chunk: 26)
#define ITERS 42            // RCH + 6 warmup, = 6*7 (ring-unroll friendly)
#define NTHR 192            // 3 waves; 160 active col-pairs cover all 320 cols

// ---------------- kernel 1: per-sample max(Y) ----------------
__global__ __launch_bounds__(256) void k_max(const float* __restrict__ Y,
                                             unsigned* __restrict__ dr) {
    int bid = blockIdx.x;
    int b = bid >> 2, part = bid & 3;
    const float4* p = (const float4*)(Y + (size_t)b * (IMH * IMW) + part * (IMH * IMW / 4));
    float m = 0.f;
    for (int i = threadIdx.x; i < (IMH * IMW / 16); i += 256) {
        float4 v = p[i];
        m = fmaxf(m, fmaxf(fmaxf(v.x, v.y), fmaxf(v.z, v.w)));
    }
    for (int off = 32; off; off >>= 1) m = fmaxf(m, __shfl_down(m, off, 64));
    __shared__ float sm[4];
    int lane = threadIdx.x & 63, wv = threadIdx.x >> 6;
    if (lane == 0) sm[wv] = m;
    __syncthreads();
    if (threadIdx.x == 0) {
        m = fmaxf(fmaxf(sm[0], sm[1]), fmaxf(sm[2], sm[3]));
        atomicMax(dr + b, __float_as_uint(m));   // Y in (0,1): uint order == float order
    }
}

// ---------------- SSIM per-pixel math (4 merged window sums) ----------------
__device__ __forceinline__ float ssim_px(float hx, float hy, float hp, float hxy,
                                         float C1, float C2) {
    const float inv = 1.f / 49.f;
    const float cn  = 49.f / 48.f;
    float ux  = hx  * inv, uy = hy * inv;
    float upp = hp  * inv;                 // mean of x^2 + y^2 window
    float uxy = hxy * inv;
    float ux2 = ux * ux, uy2 = uy * uy, uxuy = ux * uy;
    float B2 = cn * (upp - ux2 - uy2) + C2;      // vx + vy + C2
    float A2 = 2.f * cn * (uxy - uxuy) + C2;     // 2*vxy + C2
    float A1 = 2.f * uxuy + C1;
    float B1 = ux2 + uy2 + C1;
    return (A1 * A2) * __builtin_amdgcn_rcpf(B1 * B2);   // rel err ~1e-5 << 2e-2 thr
}

// ---------------- kernel 2: fused box filters + SSIM + partial sum ----------------
// Thread t owns input columns {2t, 2t+1} (float2). Vertical 7-row sliding sums
// in registers (static ring via 7-unrolled bodies). Horizontal 7-tap via LDS
// column-sum exchange: 4 x ds_write_b64 + 16 x ds_read_b64 per wave-row for
// 128 output pixels (vs 40 scalar DS ops per 64 px before).
__global__ __launch_bounds__(NTHR) void k_ssim(const float* __restrict__ X,
                                               const float* __restrict__ Y,
                                               const unsigned* __restrict__ dr,
                                               double* __restrict__ acc) {
    const int idx = blockIdx.x;
    const int b  = idx / NCH;
    const int rc = idx - b * NCH;
    const int t  = threadIdx.x;
    const int r0 = rc * RCH;
    const int nout = min(RCH, OUTD - r0);
    const bool act = (t < IMW / 2);            // 160 writers
    const bool rdr = (t <= (OUTD - 2) / 2);    // t<=156: outputs 2t, 2t+1 both < 314

    const float2* Xp = (const float2*)(X + (size_t)b * (IMH * IMW));
    const float2* Yp = (const float2*)(Y + (size_t)b * (IMH * IMW));

    const float drv = __uint_as_float(dr[b]);
    const float c1s = 0.01f * drv, c2s = 0.03f * drv;
    const float C1 = c1s * c1s, C2 = c2s * c2s;

    // parity-double-buffered column sums; float2 keeps b64 alignment
    __shared__ float2 vs[2][4][NTHR + 4];

    float2 rx[7], ry[7];
    #pragma unroll
    for (int k = 0; k < 7; ++k) { rx[k] = make_float2(0.f, 0.f); ry[k] = make_float2(0.f, 0.f); }
    float2 sx  = make_float2(0.f, 0.f), sy  = make_float2(0.f, 0.f);
    float2 sp  = make_float2(0.f, 0.f), sxy = make_float2(0.f, 0.f);
    float part = 0.f;

    // One barrier per row is safe: row i writes/reads buffer (i&1); a wave
    // ahead writes (i&1)^1 which nobody is still reading, and it cannot
    // reach the NEXT write of (i&1) without passing the barrier every
    // thread only reaches after finishing its reads of (i&1).
    #define VBODY(K, I7) {                                                     \
        const int i = (I7) + (K);                                              \
        const int r = r0 + i;                                                  \
        float2 xn = make_float2(0.f, 0.f), yn = make_float2(0.f, 0.f);         \
        if (act && r < IMH) { xn = Xp[r * (IMW/2) + t]; yn = Yp[r * (IMW/2) + t]; } \
        const float2 ox = rx[K], oy = ry[K];                                   \
        sx.x  += xn.x - ox.x;              sx.y  += xn.y - ox.y;               \
        sy.x  += yn.x - oy.x;              sy.y  += yn.y - oy.y;               \
        sp.x  += (xn.x*xn.x + yn.x*yn.x) - (ox.x*ox.x + oy.x*oy.x);            \
        sp.y  += (xn.y*xn.y + yn.y*yn.y) - (ox.y*ox.y + oy.y*oy.y);            \
        sxy.x += xn.x*yn.x - ox.x*oy.x;    sxy.y += xn.y*yn.y - ox.y*oy.y;     \
        rx[K] = xn; ry[K] = yn;                                                \
        if (i >= 6) {                      /* uniform branch */                \
            const int par = i & 1;                                             \
            if (act) { vs[par][0][t] = sx;  vs[par][1][t] = sy;                \
                       vs[par][2][t] = sp;  vs[par][3][t] = sxy; }             \
            __syncthreads();                                                   \
            if (rdr && (i - 6 < nout)) {                                       \
                float h0[4], h1[4];                                            \
                _Pragma("unroll")                                              \
                for (int q = 0; q < 4; ++q) {                                  \
                    float2 v0 = vs[par][q][t],     v1 = vs[par][q][t + 1];     \
                    float2 v2 = vs[par][q][t + 2], v3 = vs[par][q][t + 3];     \
                    float s8 = ((v0.x + v0.y) + (v1.x + v1.y))                 \
                             + ((v2.x + v2.y) + (v3.x + v3.y));                \
                    h0[q] = s8 - v3.y;     /* taps 0..6 for col 2t   */        \
                    h1[q] = s8 - v0.x;     /* taps 1..7 for col 2t+1 */        \
                }                                                              \
                part += ssim_px(h0[0], h0[1], h0[2], h0[3], C1, C2);           \
                part += ssim_px(h1[0], h1[1], h1[2], h1[3], C1, C2);           \
            }                                                                  \
        }                                                                      \
    }

    for (int i7 = 0; i7 < ITERS; i7 += 7) {
        VBODY(0, i7) VBODY(1, i7) VBODY(2, i7) VBODY(3, i7)
        VBODY(4, i7) VBODY(5, i7) VBODY(6, i7)
    }
    #undef VBODY

    // block reduction (3 waves)
    for (int off = 32; off; off >>= 1) part += __shfl_down(part, off, 64);
    __shared__ float ps[3];
    const int lane = t & 63, wv = t >> 6;
    if (lane == 0) ps[wv] = part;
    __syncthreads();
    if (t == 0) atomicAdd(acc, (double)((ps[0] + ps[1]) + ps[2]));
}

// ---------------- kernel 3: finalize ----------------
__global__ void k_final(const double* __restrict__ acc, float* __restrict__ out) {
    const double cnt = (double)BATCH * (double)OUTD * (double)OUTD;
    out[0] = (float)(1.0 - acc[0] / cnt);
}

extern "C" void kernel_launch(void* const* d_in, const int* in_sizes, int n_in,
                              void* d_out, int out_size, void* d_ws, size_t ws_size,
                              hipStream_t stream) {
    const float* X = (const float*)d_in[0];
    const float* Y = (const float*)d_in[1];
    float* out = (float*)d_out;

    unsigned* dr = (unsigned*)d_ws;                      // 256 * 4 B
    double* acc  = (double*)((char*)d_ws + 1024);        // 8 B, aligned

    hipMemsetAsync(d_ws, 0, 2048, stream);
    k_max <<<BATCH * 4, 256, 0, stream>>>(Y, dr);
    k_ssim<<<BATCH * NCH, NTHR, 0, stream>>>(X, Y, dr, acc);
    k_final<<<1, 1, 0, stream>>>(acc, out);
}

// Round 8
// 276.590 us; speedup vs baseline: 1.1536x; 1.0169x over previous
//
#include <hip/hip_runtime.h>

#define BATCH 256
#define IMH 320
#define IMW 320
#define OUTD 314            // 320 - 7 + 1
#define NCH 9               // row chunks per sample
#define RCH 36              // output rows per chunk (last chunk: 26)
#define ITERS 42            // RCH + 6 warmup
#define NTHR 192            // 3 waves; each wave = one autonomous column strip

// ---------------- kernel 1: per-sample max(Y) ----------------
__global__ __launch_bounds__(256) void k_max(const float* __restrict__ Y,
                                             unsigned* __restrict__ dr) {
    int bid = blockIdx.x;
    int b = bid >> 2, part = bid & 3;
    const float4* p = (const float4*)(Y + (size_t)b * (IMH * IMW) + part * (IMH * IMW / 4));
    float m = 0.f;
    for (int i = threadIdx.x; i < (IMH * IMW / 16); i += 256) {
        float4 v = p[i];
        m = fmaxf(m, fmaxf(fmaxf(v.x, v.y), fmaxf(v.z, v.w)));
    }
    for (int off = 32; off; off >>= 1) m = fmaxf(m, __shfl_down(m, off, 64));
    __shared__ float sm[4];
    int lane = threadIdx.x & 63, wv = threadIdx.x >> 6;
    if (lane == 0) sm[wv] = m;
    __syncthreads();
    if (threadIdx.x == 0) {
        m = fmaxf(fmaxf(sm[0], sm[1]), fmaxf(sm[2], sm[3]));
        atomicMax(dr + b, __float_as_uint(m));   // Y in (0,1): uint order == float order
    }
}

// ---------------- SSIM per-pixel math (4 merged window sums) ----------------
__device__ __forceinline__ float ssim_px(float hx, float hy, float hp, float hxy,
                                         float C1, float C2) {
    const float inv = 1.f / 49.f;
    const float cn  = 49.f / 48.f;
    float ux  = hx  * inv, uy = hy * inv;
    float upp = hp  * inv;                 // mean of x^2 + y^2 window
    float uxy = hxy * inv;
    float ux2 = ux * ux, uy2 = uy * uy, uxuy = ux * uy;
    float B2 = cn * (upp - ux2 - uy2) + C2;      // vx + vy + C2
    float A2 = 2.f * cn * (uxy - uxuy) + C2;     // 2*vxy + C2
    float A1 = 2.f * uxuy + C1;
    float B1 = ux2 + uy2 + C1;
    return (A1 * A2) * __builtin_amdgcn_rcpf(B1 * B2);   // rel err ~1e-5 << 2e-2 thr
}

__device__ __forceinline__ float bperm(int addr, float v) {
    return __int_as_float(__builtin_amdgcn_ds_bpermute(addr, __float_as_int(v)));
}

// ---------------- kernel 2: barrier-free fused box filter + SSIM ----------------
// Each wave owns a 128-col input strip (lane l -> float2 cols base+2l, base+2l+1).
// Vertical 7-row sliding sums in registers (static ring). Horizontal 7-tap via
// ds_bpermute from lanes l+1..l+3 (4 bpermutes per quantity). NO __syncthreads
// in the row loop -> waves drift independently, latency hides across 27 waves/CU.
__global__ __launch_bounds__(NTHR) void k_ssim(const float* __restrict__ X,
                                               const float* __restrict__ Y,
                                               const unsigned* __restrict__ dr,
                                               double* __restrict__ acc) {
    const int idx = blockIdx.x;
    const int b  = idx / NCH;
    const int rc = idx - b * NCH;
    const int t  = threadIdx.x;
    const int w  = t >> 6;
    const int l  = t & 63;
    const int r0 = rc * RCH;
    const int nout = min(RCH, OUTD - r0);

    // strip bases chosen so all loads stay in [0,320): outputs owned
    // wave0: 0..121 (lanes 0..60), wave1: 122..243 (lanes 0..60),
    // wave2: 244..313 (lanes 26..60; lanes 0..25 are providers only)
    const int in_base = (w == 0) ? 0 : (w == 1 ? 122 : 192);
    const int lane_lo = (w == 2) ? 26 : 0;
    const bool valid = (l >= lane_lo) && (l <= 60);

    const float2* Xp = (const float2*)(X + (size_t)b * (IMH * IMW)) + (in_base >> 1) + l;
    const float2* Yp = (const float2*)(Y + (size_t)b * (IMH * IMW)) + (in_base >> 1) + l;

    // bpermute byte addresses (lane*4), computed once
    const int a1 = ((l + 1) & 63) << 2;
    const int a2 = ((l + 2) & 63) << 2;
    const int a3 = ((l + 3) & 63) << 2;

    const float drv = __uint_as_float(dr[b]);
    const float c1s = 0.01f * drv, c2s = 0.03f * drv;
    const float C1 = c1s * c1s, C2 = c2s * c2s;

    float2 rx[7], ry[7];
    #pragma unroll
    for (int k = 0; k < 7; ++k) { rx[k] = make_float2(0.f, 0.f); ry[k] = make_float2(0.f, 0.f); }
    float2 sx  = make_float2(0.f, 0.f), sy  = make_float2(0.f, 0.f);
    float2 sp  = make_float2(0.f, 0.f), sxy = make_float2(0.f, 0.f);
    float part = 0.f;

    // horizontal 7-tap from 4 lane-pairs: S8 = sum of pairs (l..l+3);
    // h0 (cols 2c..2c+6)  = S8 - y(l+3);  h1 (cols 2c+1..2c+7) = S8 - x(own)
    #define HQ(q, h0, h1) {                                                    \
        float s2_ = q.x + q.y;                                                 \
        float b1_ = bperm(a1, s2_);                                            \
        float b2_ = bperm(a2, s2_);                                            \
        float b3_ = bperm(a3, s2_);                                            \
        float y3_ = bperm(a3, q.y);                                            \
        float S8_ = (s2_ + b1_) + (b2_ + b3_);                                 \
        h0 = S8_ - y3_;  h1 = S8_ - q.x; }

    #define VBODY(K, I7) {                                                     \
        const int i = (I7) + (K);                                              \
        const int r = r0 + i;                                                  \
        float2 xn = make_float2(0.f, 0.f), yn = make_float2(0.f, 0.f);         \
        if (r < IMH) { xn = Xp[r * (IMW/2)]; yn = Yp[r * (IMW/2)]; }           \
        const float2 ox = rx[K], oy = ry[K];                                   \
        sx.x  += xn.x - ox.x;              sx.y  += xn.y - ox.y;               \
        sy.x  += yn.x - oy.x;              sy.y  += yn.y - oy.y;               \
        sp.x  += (xn.x*xn.x + yn.x*yn.x) - (ox.x*ox.x + oy.x*oy.x);            \
        sp.y  += (xn.y*xn.y + yn.y*yn.y) - (ox.y*ox.y + oy.y*oy.y);            \
        sxy.x += xn.x*yn.x - ox.x*oy.x;    sxy.y += xn.y*yn.y - ox.y*oy.y;     \
        rx[K] = xn; ry[K] = yn;                                                \
        if (i >= 6 && (i - 6) < nout) {    /* uniform: all lanes provide */    \
            float hx0,hx1,hy0,hy1,hp0,hp1,hq0,hq1;                             \
            HQ(sx,  hx0, hx1)                                                  \
            HQ(sy,  hy0, hy1)                                                  \
            HQ(sp,  hp0, hp1)                                                  \
            HQ(sxy, hq0, hq1)                                                  \
            float s0 = ssim_px(hx0, hy0, hp0, hq0, C1, C2);                    \
            float s1 = ssim_px(hx1, hy1, hp1, hq1, C1, C2);                    \
            part += valid ? (s0 + s1) : 0.f;                                   \
        }                                                                      \
    }

    for (int i7 = 0; i7 < ITERS; i7 += 7) {
        VBODY(0, i7) VBODY(1, i7) VBODY(2, i7) VBODY(3, i7)
        VBODY(4, i7) VBODY(5, i7) VBODY(6, i7)
    }
    #undef VBODY
    #undef HQ

    // block reduction (3 waves) — only sync point in the kernel
    for (int off = 32; off; off >>= 1) part += __shfl_down(part, off, 64);
    __shared__ float ps[3];
    if (l == 0) ps[w] = part;
    __syncthreads();
    if (t == 0) atomicAdd(acc, (double)((ps[0] + ps[1]) + ps[2]));
}

// ---------------- kernel 3: finalize ----------------
__global__ void k_final(const double* __restrict__ acc, float* __restrict__ out) {
    const double cnt = (double)BATCH * (double)OUTD * (double)OUTD;
    out[0] = (float)(1.0 - acc[0] / cnt);
}

extern "C" void kernel_launch(void* const* d_in, const int* in_sizes, int n_in,
                              void* d_out, int out_size, void* d_ws, size_t ws_size,
                              hipStream_t stream) {
    const float* X = (const float*)d_in[0];
    const float* Y = (const float*)d_in[1];
    float* out = (float*)d_out;

    unsigned* dr = (unsigned*)d_ws;                      // 256 * 4 B
    double* acc  = (double*)((char*)d_ws + 1024);        // 8 B, aligned

    hipMemsetAsync(d_ws, 0, 2048, stream);
    k_max <<<BATCH * 4, 256, 0, stream>>>(Y, dr);
    k_ssim<<<BATCH * NCH, NTHR, 0, stream>>>(X, Y, dr, acc);
    k_final<<<1, 1, 0, stream>>>(acc, out);
}